// Round 10
// baseline (22.843 us; speedup 1.0000x reference)
//
#include <hip/hip_runtime.h>

// YOLOv3 loss on MI355X — round 10: single compute node + gather spreading.
// Graph = memset(256B: acc[30]+counter) + fused kernel (467 x 512).
//  - EVERY block gathers 365 noobj ch-4 cells (load issued first, misses
//    overlap correct work; balanced ~665 lines/CU instead of 1024).
//  - blocks [0,300): also correct region — one wave per (scale,b,t).
//  - partials -> device-scope returning atomicAdd into acc[30] (coherent pt);
//    __syncthreads drain; counter++; LAST block spins on counter==NBLK,
//    atomic-reads acc, computes the scalar loss. NO __threadfence (R4 lesson).

#define NB 16      // batch
#define NT 50      // targets per batch
#define NA 3       // anchors
#define NC 80      // classes
#define NCORR 300  // correct blocks (300*8 waves = 2400 = 3*16*50)
#define NBLK 467
#define CPB 365    // gather cells per block (467*365 >= 170352)
#define CT 170352
#define C0S 8112
#define C01S 40560

__device__ __forceinline__ float bce0(float p) { return -log1pf(-p); } // target 0
__device__ __forceinline__ float bce1(float p) { return -logf(p); }    // target 1

// acc layout: [scale*9 + {0..3 mse,4 obj,5 noobj_corr,6 cls,7 n_pos,8 n_zeroed}],
//             [27+scale] = noobj gather sums
__global__ __launch_bounds__(512) void fused_kernel(
    const float* __restrict__ o13,
    const float* __restrict__ o26,
    const float* __restrict__ o52,
    const float* __restrict__ targets,
    const float* __restrict__ a13,
    const float* __restrict__ a26,
    const float* __restrict__ a52,
    float* __restrict__ acc,        // [30], zeroed by memset node
    unsigned* __restrict__ counter, // [1], zeroed by memset node
    float* __restrict__ outp)
{
    __shared__ float sacc[32];
    __shared__ float red[8][3];

    int lane = threadIdx.x & 63;
    int wvid = threadIdx.x >> 6;

    // ---- issue gather load FIRST (miss flies under everything below) ----
    int gidx = blockIdx.x * CPB + threadIdx.x;
    bool gvalid = (threadIdx.x < CPB) && (gidx < CT);
    int gcell = gvalid ? gidx : 0;
    const float* gp; int gsc;
    if (gcell < C0S)       { gp = o13 + (size_t)gcell * 85 + 4;          gsc = 0; }
    else if (gcell < C01S) { gp = o26 + (size_t)(gcell - C0S) * 85 + 4;  gsc = 1; }
    else                   { gp = o52 + (size_t)(gcell - C01S) * 85 + 4; gsc = 2; }
    float gv = *gp;

    if (threadIdx.x < 30) sacc[threadIdx.x] = 0.0f;
    __syncthreads();

    if (blockIdx.x < NCORR) {
        // ---------------- correct region ----------------
        int wid = blockIdx.x * 8 + wvid;            // 0..2399
        int scale = wid / (NB * NT);
        int rem   = wid - scale * (NB * NT);
        int b = rem / NT, t = rem - b * NT;

        int G = (scale == 0) ? 13 : (scale == 1) ? 26 : 52;
        const float* out  = (scale == 0) ? o13 : (scale == 1) ? o26 : o52;
        const float* anch = (scale == 0) ? a13 : (scale == 1) ? a26 : a52;

        // in-register build: lane l computes target l's record
        unsigned mt = 0xFFFFFFFFu;
        float tx = 0.0f, ty = 0.0f, tw = 0.0f, th = 0.0f;
        {
            int li = (lane < NT) ? lane : NT - 1;   // clamped addr, masked below
            const float* tg = targets + ((size_t)b * NT + li) * 5;
            float4 t4 = *(const float4*)tg;
            float x1 = t4.x, y1 = t4.y, x2 = t4.z, y2 = t4.w;
            int cls = (int)tg[4];
            float gf = (float)G;
            float bx = 0.5f * (x1 + x2) * gf;
            float by = 0.5f * (y1 + y2) * gf;
            float bw = (x2 - x1) * gf;
            float bh = (y2 - y1) * gf;
            int best = 0; float bestiou = -1.0f, aw_b = 1.0f, ah_b = 1.0f;
            unsigned nmz = 0;
            #pragma unroll
            for (int a = 0; a < NA; ++a) {
                float aw = anch[2 * a], ah = anch[2 * a + 1];
                float inter = fminf(aw, bw) * fminf(ah, bh);
                float uni = 1e-8f + aw * ah + bw * bh - inter;
                float iou = inter / uni;
                if (iou > 0.5f) nmz |= (1u << a);
                if (iou > bestiou) { bestiou = iou; best = a; aw_b = aw; ah_b = ah; }
            }
            int gi = (int)bx; gi = gi < 0 ? 0 : (gi > G - 1 ? G - 1 : gi);
            int gj = (int)by; gj = gj < 0 ? 0 : (gj > G - 1 ? G - 1 : gj);
            tx = bx - floorf(bx);
            ty = by - floorf(by);
            tw = logf(bw / aw_b);
            th = logf(bh / ah_b);
            if (lane < NT)
                mt = (unsigned)gi | ((unsigned)gj << 6) | ((unsigned)best << 12)
                   | ((unsigned)cls << 14) | (nmz << 21);
        }

        unsigned key_lane = mt & 0xFFFu;
        unsigned key_t = __shfl(key_lane, t);
        int gi = key_t & 63, gj = (key_t >> 6) & 63;

        // ---- issue all 6 cell loads before ballots ----
        const float* pc0 = out + (((size_t)(b * NA + 0) * G + gj) * G + gi) * 85;
        const float* pc1 = out + (((size_t)(b * NA + 1) * G + gj) * G + gi) * 85;
        const float* pc2 = out + (((size_t)(b * NA + 2) * G + gj) * G + gi) * 85;
        float vlo0 = pc0[lane], vlo1 = pc1[lane], vlo2 = pc2[lane];
        int hl = (lane < 21) ? 64 + lane : lane;
        float vhi0 = pc0[hl], vhi1 = pc1[hl], vhi2 = pc2[hl];

        unsigned long long match = __ballot(lane < NT && key_lane == key_t);
        bool canon = ((match & ((1ull << t) - 1ull)) == 0ull);   // wave-uniform

        if (canon) {
            bool mk = (lane < NT) && (key_lane == key_t);
            int bsel = (mt >> 12) & 3;
            unsigned long long bm0 = __ballot(mk && bsel == 0);
            unsigned long long bm1 = __ballot(mk && bsel == 1);
            unsigned long long bm2 = __ballot(mk && bsel == 2);
            unsigned long long nz0 = __ballot(mk && ((mt >> 21) & 1u));
            unsigned long long nz1 = __ballot(mk && ((mt >> 22) & 1u));
            unsigned long long nz2 = __ballot(mk && ((mt >> 23) & 1u));
            int myc = (mt >> 14) & 127;

            #define ANCHOR_BLOCK(A, BM, NZ, VLO, VHI)                                   \
            {                                                                           \
                bool pos = (BM) != 0ull;                                                \
                if (pos || (NZ) != 0ull) {                                              \
                    if (lane == 4) {                    /* noobj correction */          \
                        atomicAdd(&sacc[scale * 9 + 5], -bce0(VLO));                    \
                        atomicAdd(&sacc[scale * 9 + 8], 1.0f);                          \
                    }                                                                   \
                    if (pos) {                                                          \
                        int lastt = 63 - __clzll(BM);   /* last-write-wins */           \
                        float ltx = __shfl(tx, lastt), lty = __shfl(ty, lastt);         \
                        float ltw = __shfl(tw, lastt), lth = __shfl(th, lastt);         \
                        unsigned c0, c1, c2;                                            \
                        if (__popcll(BM) == 1) {        /* single writer: 1 shfl */     \
                            int lc = __shfl(myc, lastt);                                \
                            c0 = (lc < 32) ? (1u << lc) : 0u;                           \
                            c1 = (lc >= 32 && lc < 64) ? (1u << (lc - 32)) : 0u;        \
                            c2 = (lc >= 64) ? (1u << (lc - 64)) : 0u;                   \
                        } else {                        /* rare: OR butterfly */        \
                            c0 = c1 = c2 = 0u;                                          \
                            if (((BM) >> lane) & 1ull) {                                \
                                if (myc < 32) c0 = 1u << myc;                           \
                                else if (myc < 64) c1 = 1u << (myc - 32);               \
                                else c2 = 1u << (myc - 64);                             \
                            }                                                           \
                            _Pragma("unroll")                                           \
                            for (int off = 32; off; off >>= 1) {                        \
                                c0 |= __shfl_xor(c0, off);                              \
                                c1 |= __shfl_xor(c1, off);                              \
                                c2 |= __shfl_xor(c2, off);                              \
                            }                                                           \
                        }                                                               \
                        float cls = 0.0f;                                               \
                        if (lane >= 5) {                /* channels 0..58 */            \
                            int c = lane - 5;                                           \
                            unsigned w = (c < 32) ? c0 : c1;                            \
                            cls += ((w >> (c & 31)) & 1u) ? bce1(VLO) : bce0(VLO);      \
                        }                                                               \
                        if (lane < 21) {                /* channels 59..79 */           \
                            int c = lane + 59;                                          \
                            unsigned w = (c < 64) ? c1 : c2;                            \
                            cls += ((w >> (c & 31)) & 1u) ? bce1(VHI) : bce0(VHI);      \
                        }                                                               \
                        _Pragma("unroll")                                               \
                        for (int off = 32; off; off >>= 1) cls += __shfl_xor(cls, off); \
                        if (lane == 0) {                                                \
                            atomicAdd(&sacc[scale * 9 + 6], cls);                       \
                            atomicAdd(&sacc[scale * 9 + 7], 1.0f);                      \
                        }                                                               \
                        if (lane < 4) {                 /* mse terms */                 \
                            float tv = (lane == 0) ? ltx : (lane == 1) ? lty            \
                                     : (lane == 2) ? ltw : lth;                         \
                            float d = VLO - tv;                                         \
                            atomicAdd(&sacc[scale * 9 + lane], d * d);                  \
                        }                                                               \
                        if (lane == 4) atomicAdd(&sacc[scale * 9 + 4], bce1(VLO));      \
                    }                                                                   \
                }                                                                       \
            }

            ANCHOR_BLOCK(0, bm0, nz0, vlo0, vhi0)
            ANCHOR_BLOCK(1, bm1, nz1, vlo1, vhi1)
            ANCHOR_BLOCK(2, bm2, nz2, vlo2, vhi2)
            #undef ANCHOR_BLOCK
        }
    }

    // ---------------- gather consume + wave reduce ----------------
    {
        float bv = gvalid ? bce0(gv) : 0.0f;
        float g0 = (gsc == 0) ? bv : 0.0f;
        float g1 = (gsc == 1) ? bv : 0.0f;
        float g2 = (gsc == 2) ? bv : 0.0f;
        #pragma unroll
        for (int off = 32; off; off >>= 1) {
            g0 += __shfl_down(g0, off);
            g1 += __shfl_down(g1, off);
            g2 += __shfl_down(g2, off);
        }
        if (lane == 0) { red[wvid][0] = g0; red[wvid][1] = g1; red[wvid][2] = g2; }
    }
    __syncthreads();
    if (threadIdx.x < 3) {
        float x = 0.0f;
        #pragma unroll
        for (int w = 0; w < 8; ++w) x += red[w][threadIdx.x];
        sacc[27 + threadIdx.x] = x;      // single writer per entry
    }
    __syncthreads();

    // ---------------- commit partials (returning atomics -> completion) ----
    if (threadIdx.x < 30) {
        float v = sacc[threadIdx.x];
        if (v != 0.0f) {
            float old = atomicAdd(&acc[threadIdx.x], v);
            asm volatile("" :: "v"(old));     // consume return: wait = completed
        }
    }
    __syncthreads();                          // barrier drain: adds done block-wide
    if (threadIdx.x == 0) atomicAdd(counter, 1u);

    // ---------------- last block finalizes ----------------
    if (blockIdx.x == NBLK - 1) {
        if (threadIdx.x == 0) {
            while (atomicAdd(counter, 0u) < (unsigned)NBLK)
                __builtin_amdgcn_s_sleep(8);
        }
        __syncthreads();
        if (threadIdx.x < 30) sacc[threadIdx.x] = atomicAdd(&acc[threadIdx.x], 0.0f);
        __syncthreads();
        if (threadIdx.x == 0) {
            const float Stot[3] = { 8112.0f, 32448.0f, 129792.0f };
            float total = 0.0f;
            #pragma unroll
            for (int sc = 0; sc < 3; ++sc) {
                float np = sacc[sc * 9 + 7];
                float nn = Stot[sc] - sacc[sc * 9 + 8];
                float noobj = sacc[27 + sc] + sacc[sc * 9 + 5];
                total += (sacc[sc*9+0] + sacc[sc*9+1] + sacc[sc*9+2]
                        + sacc[sc*9+3] + sacc[sc*9+4]) / np
                       + noobj / nn * 100.0f
                       + sacc[sc*9+6] / (np * (float)NC);
            }
            outp[0] = total;
        }
    }
}

extern "C" void kernel_launch(void* const* d_in, const int* in_sizes, int n_in,
                              void* d_out, int out_size, void* d_ws, size_t ws_size,
                              hipStream_t stream)
{
    const float* out13   = (const float*)d_in[0];
    const float* out26   = (const float*)d_in[1];
    const float* out52   = (const float*)d_in[2];
    const float* targets = (const float*)d_in[3];
    const float* a13     = (const float*)d_in[4];
    const float* a26     = (const float*)d_in[5];
    const float* a52     = (const float*)d_in[6];

    // ws: acc[30] at 0; counter at 128
    float*    acc     = (float*)d_ws;
    unsigned* counter = (unsigned*)((char*)d_ws + 128);

    hipMemsetAsync(d_ws, 0, 256, stream);

    fused_kernel<<<NBLK, 512, 0, stream>>>(
        out13, out26, out52, targets, a13, a26, a52, acc, counter, (float*)d_out);
}

// Round 11
// 22.282 us; speedup vs baseline: 1.0252x; 1.0252x over previous
//
#include <hip/hip_runtime.h>

// YOLOv3 loss on MI355X — round 11: R8 two-node skeleton + gather spread.
// main_kernel (467 x 512):
//   - EVERY block: issue 365 noobj ch-4 gather loads as the FIRST instruction
//     (one per thread, tid<365); misses overlap all later work.
//   - blocks [0,300): correct region — 8 waves, one wave per (scale,b,t);
//     in-register build; 6 cell loads before ballots; single-writer class path.
//   - partials to pitched slot table sall[30][512]: rows 0..26 only by correct
//     blocks, rows 27..29 (gather) by all blocks. No zero-init needed.
// final_kernel: 1 x 256, sums row ranges, computes scalar loss.

#define NB 16      // batch
#define NT 50      // targets per batch
#define NA 3       // anchors
#define NC 80      // classes
#define NCORR 300  // correct blocks (300*8 waves = 2400 = 3*16*50)
#define NBLK 467
#define PITCH 512
#define CPB 365    // gather cells per block (467*365 >= 170352)
#define CT 170352
#define C0S 8112
#define C01S 40560

__device__ __forceinline__ float bce0(float p) { return -log1pf(-p); } // target 0
__device__ __forceinline__ float bce1(float p) { return -logf(p); }    // target 1

// sall rows: scale*9 + {0..3 mse,4 obj,5 noobj_corr,6 cls,7 n_pos,8 n_zeroed};
//            27+scale = gather noobj sums
__global__ __launch_bounds__(512) void main_kernel(
    const float* __restrict__ o13,
    const float* __restrict__ o26,
    const float* __restrict__ o52,
    const float* __restrict__ targets,
    const float* __restrict__ a13,
    const float* __restrict__ a26,
    const float* __restrict__ a52,
    float* __restrict__ sall)       // [30][PITCH]
{
    __shared__ float sacc[32];
    __shared__ float red[8][3];

    int lane = threadIdx.x & 63;
    int wvid = threadIdx.x >> 6;

    // ---- issue gather load FIRST (miss flies under everything below) ----
    int gidx = blockIdx.x * CPB + threadIdx.x;
    bool gvalid = (threadIdx.x < CPB) && (gidx < CT);
    int gcell = gvalid ? gidx : 0;
    const float* gp; int gsc;
    if (gcell < C0S)       { gp = o13 + (size_t)gcell * 85 + 4;          gsc = 0; }
    else if (gcell < C01S) { gp = o26 + (size_t)(gcell - C0S) * 85 + 4;  gsc = 1; }
    else                   { gp = o52 + (size_t)(gcell - C01S) * 85 + 4; gsc = 2; }
    float gv = *gp;

    if (threadIdx.x < 30) sacc[threadIdx.x] = 0.0f;
    __syncthreads();

    if (blockIdx.x < NCORR) {
        // ---------------- correct region ----------------
        int wid = blockIdx.x * 8 + wvid;            // 0..2399
        int scale = wid / (NB * NT);
        int rem   = wid - scale * (NB * NT);
        int b = rem / NT, t = rem - b * NT;

        int G = (scale == 0) ? 13 : (scale == 1) ? 26 : 52;
        const float* out  = (scale == 0) ? o13 : (scale == 1) ? o26 : o52;
        const float* anch = (scale == 0) ? a13 : (scale == 1) ? a26 : a52;

        // in-register build: lane l computes target l's record
        unsigned mt = 0xFFFFFFFFu;
        float tx = 0.0f, ty = 0.0f, tw = 0.0f, th = 0.0f;
        {
            int li = (lane < NT) ? lane : NT - 1;   // clamped addr, masked below
            const float* tg = targets + ((size_t)b * NT + li) * 5;
            float4 t4 = *(const float4*)tg;
            float x1 = t4.x, y1 = t4.y, x2 = t4.z, y2 = t4.w;
            int cls = (int)tg[4];
            float gf = (float)G;
            float bx = 0.5f * (x1 + x2) * gf;
            float by = 0.5f * (y1 + y2) * gf;
            float bw = (x2 - x1) * gf;
            float bh = (y2 - y1) * gf;
            int best = 0; float bestiou = -1.0f, aw_b = 1.0f, ah_b = 1.0f;
            unsigned nmz = 0;
            #pragma unroll
            for (int a = 0; a < NA; ++a) {
                float aw = anch[2 * a], ah = anch[2 * a + 1];
                float inter = fminf(aw, bw) * fminf(ah, bh);
                float uni = 1e-8f + aw * ah + bw * bh - inter;
                float iou = inter / uni;
                if (iou > 0.5f) nmz |= (1u << a);
                if (iou > bestiou) { bestiou = iou; best = a; aw_b = aw; ah_b = ah; }
            }
            int gi = (int)bx; gi = gi < 0 ? 0 : (gi > G - 1 ? G - 1 : gi);
            int gj = (int)by; gj = gj < 0 ? 0 : (gj > G - 1 ? G - 1 : gj);
            tx = bx - floorf(bx);
            ty = by - floorf(by);
            tw = logf(bw / aw_b);
            th = logf(bh / ah_b);
            if (lane < NT)
                mt = (unsigned)gi | ((unsigned)gj << 6) | ((unsigned)best << 12)
                   | ((unsigned)cls << 14) | (nmz << 21);
        }

        unsigned key_lane = mt & 0xFFFu;
        unsigned key_t = __shfl(key_lane, t);
        int gi = key_t & 63, gj = (key_t >> 6) & 63;

        // ---- issue all 6 cell loads before ballots ----
        const float* pc0 = out + (((size_t)(b * NA + 0) * G + gj) * G + gi) * 85;
        const float* pc1 = out + (((size_t)(b * NA + 1) * G + gj) * G + gi) * 85;
        const float* pc2 = out + (((size_t)(b * NA + 2) * G + gj) * G + gi) * 85;
        float vlo0 = pc0[lane], vlo1 = pc1[lane], vlo2 = pc2[lane];
        int hl = (lane < 21) ? 64 + lane : lane;
        float vhi0 = pc0[hl], vhi1 = pc1[hl], vhi2 = pc2[hl];

        unsigned long long match = __ballot(lane < NT && key_lane == key_t);
        bool canon = ((match & ((1ull << t) - 1ull)) == 0ull);   // wave-uniform

        if (canon) {
            bool mk = (lane < NT) && (key_lane == key_t);
            int bsel = (mt >> 12) & 3;
            unsigned long long bm0 = __ballot(mk && bsel == 0);
            unsigned long long bm1 = __ballot(mk && bsel == 1);
            unsigned long long bm2 = __ballot(mk && bsel == 2);
            unsigned long long nz0 = __ballot(mk && ((mt >> 21) & 1u));
            unsigned long long nz1 = __ballot(mk && ((mt >> 22) & 1u));
            unsigned long long nz2 = __ballot(mk && ((mt >> 23) & 1u));
            int myc = (mt >> 14) & 127;

            #define ANCHOR_BLOCK(A, BM, NZ, VLO, VHI)                                   \
            {                                                                           \
                bool pos = (BM) != 0ull;                                                \
                if (pos || (NZ) != 0ull) {                                              \
                    if (lane == 4) {                    /* noobj correction */          \
                        atomicAdd(&sacc[scale * 9 + 5], -bce0(VLO));                    \
                        atomicAdd(&sacc[scale * 9 + 8], 1.0f);                          \
                    }                                                                   \
                    if (pos) {                                                          \
                        int lastt = 63 - __clzll(BM);   /* last-write-wins */           \
                        float ltx = __shfl(tx, lastt), lty = __shfl(ty, lastt);         \
                        float ltw = __shfl(tw, lastt), lth = __shfl(th, lastt);         \
                        unsigned c0, c1, c2;                                            \
                        if (__popcll(BM) == 1) {        /* single writer: 1 shfl */     \
                            int lc = __shfl(myc, lastt);                                \
                            c0 = (lc < 32) ? (1u << lc) : 0u;                           \
                            c1 = (lc >= 32 && lc < 64) ? (1u << (lc - 32)) : 0u;        \
                            c2 = (lc >= 64) ? (1u << (lc - 64)) : 0u;                   \
                        } else {                        /* rare: OR butterfly */        \
                            c0 = c1 = c2 = 0u;                                          \
                            if (((BM) >> lane) & 1ull) {                                \
                                if (myc < 32) c0 = 1u << myc;                           \
                                else if (myc < 64) c1 = 1u << (myc - 32);               \
                                else c2 = 1u << (myc - 64);                             \
                            }                                                           \
                            _Pragma("unroll")                                           \
                            for (int off = 32; off; off >>= 1) {                        \
                                c0 |= __shfl_xor(c0, off);                              \
                                c1 |= __shfl_xor(c1, off);                              \
                                c2 |= __shfl_xor(c2, off);                              \
                            }                                                           \
                        }                                                               \
                        float cls = 0.0f;                                               \
                        if (lane >= 5) {                /* channels 0..58 */            \
                            int c = lane - 5;                                           \
                            unsigned w = (c < 32) ? c0 : c1;                            \
                            cls += ((w >> (c & 31)) & 1u) ? bce1(VLO) : bce0(VLO);      \
                        }                                                               \
                        if (lane < 21) {                /* channels 59..79 */           \
                            int c = lane + 59;                                          \
                            unsigned w = (c < 64) ? c1 : c2;                            \
                            cls += ((w >> (c & 31)) & 1u) ? bce1(VHI) : bce0(VHI);      \
                        }                                                               \
                        _Pragma("unroll")                                               \
                        for (int off = 32; off; off >>= 1) cls += __shfl_xor(cls, off); \
                        if (lane == 0) {                                                \
                            atomicAdd(&sacc[scale * 9 + 6], cls);                       \
                            atomicAdd(&sacc[scale * 9 + 7], 1.0f);                      \
                        }                                                               \
                        if (lane < 4) {                 /* mse terms */                 \
                            float tv = (lane == 0) ? ltx : (lane == 1) ? lty            \
                                     : (lane == 2) ? ltw : lth;                         \
                            float d = VLO - tv;                                         \
                            atomicAdd(&sacc[scale * 9 + lane], d * d);                  \
                        }                                                               \
                        if (lane == 4) atomicAdd(&sacc[scale * 9 + 4], bce1(VLO));      \
                    }                                                                   \
                }                                                                       \
            }

            ANCHOR_BLOCK(0, bm0, nz0, vlo0, vhi0)
            ANCHOR_BLOCK(1, bm1, nz1, vlo1, vhi1)
            ANCHOR_BLOCK(2, bm2, nz2, vlo2, vhi2)
            #undef ANCHOR_BLOCK
        }
    }

    // ---------------- gather consume + wave reduce ----------------
    {
        float bv = gvalid ? bce0(gv) : 0.0f;
        float g0 = (gsc == 0) ? bv : 0.0f;
        float g1 = (gsc == 1) ? bv : 0.0f;
        float g2 = (gsc == 2) ? bv : 0.0f;
        #pragma unroll
        for (int off = 32; off; off >>= 1) {
            g0 += __shfl_down(g0, off);
            g1 += __shfl_down(g1, off);
            g2 += __shfl_down(g2, off);
        }
        if (lane == 0) { red[wvid][0] = g0; red[wvid][1] = g1; red[wvid][2] = g2; }
    }
    __syncthreads();
    if (threadIdx.x < 3) {
        float x = 0.0f;
        #pragma unroll
        for (int w = 0; w < 8; ++w) x += red[w][threadIdx.x];
        sacc[27 + threadIdx.x] = x;      // single writer per entry
    }
    __syncthreads();

    // ---------------- write partial slots ----------------
    if (blockIdx.x < NCORR) {
        if (threadIdx.x < 30)
            sall[threadIdx.x * PITCH + blockIdx.x] = sacc[threadIdx.x];
    } else {
        if (threadIdx.x >= 27 && threadIdx.x < 30)
            sall[threadIdx.x * PITCH + blockIdx.x] = sacc[threadIdx.x];
    }
}

// ---------------- final: reduce slots + combine scales ----------------
__global__ __launch_bounds__(256) void final_kernel(
    const float* __restrict__ sall, float* __restrict__ outp)
{
    float s[30];
    #pragma unroll
    for (int j = 0; j < 30; ++j) s[j] = 0.0f;
    for (int c = threadIdx.x; c < NCORR; c += 256) {
        #pragma unroll
        for (int j = 0; j < 27; ++j) s[j] += sall[j * PITCH + c];
    }
    for (int c = threadIdx.x; c < NBLK; c += 256) {
        #pragma unroll
        for (int j = 27; j < 30; ++j) s[j] += sall[j * PITCH + c];
    }
    __shared__ float red[4][30];
    int lane = threadIdx.x & 63, wv = threadIdx.x >> 6;
    #pragma unroll
    for (int j = 0; j < 30; ++j) {
        float x = s[j];
        #pragma unroll
        for (int off = 32; off; off >>= 1) x += __shfl_down(x, off);
        if (lane == 0) red[wv][j] = x;
    }
    __syncthreads();
    if (threadIdx.x == 0) {
        float a[30];
        #pragma unroll
        for (int j = 0; j < 30; ++j)
            a[j] = red[0][j] + red[1][j] + red[2][j] + red[3][j];
        const float Stot[3] = { 8112.0f, 32448.0f, 129792.0f };
        float total = 0.0f;
        #pragma unroll
        for (int sc = 0; sc < 3; ++sc) {
            float np = a[sc * 9 + 7];
            float nn = Stot[sc] - a[sc * 9 + 8];
            float noobj = a[27 + sc] + a[sc * 9 + 5];
            total += (a[sc*9+0] + a[sc*9+1] + a[sc*9+2] + a[sc*9+3] + a[sc*9+4]) / np
                   + noobj / nn * 100.0f
                   + a[sc*9+6] / (np * (float)NC);
        }
        outp[0] = total;
    }
}

extern "C" void kernel_launch(void* const* d_in, const int* in_sizes, int n_in,
                              void* d_out, int out_size, void* d_ws, size_t ws_size,
                              hipStream_t stream)
{
    const float* out13   = (const float*)d_in[0];
    const float* out26   = (const float*)d_in[1];
    const float* out52   = (const float*)d_in[2];
    const float* targets = (const float*)d_in[3];
    const float* a13     = (const float*)d_in[4];
    const float* a26     = (const float*)d_in[5];
    const float* a52     = (const float*)d_in[6];

    float* sall = (float*)d_ws;     // [30][512] = 61440 B

    main_kernel<<<NBLK, 512, 0, stream>>>(
        out13, out26, out52, targets, a13, a26, a52, sall);

    final_kernel<<<1, 256, 0, stream>>>(sall, (float*)d_out);
}

// Round 12
// 21.296 us; speedup vs baseline: 1.0726x; 1.0463x over previous
//
#include <hip/hip_runtime.h>

// YOLOv3 loss on MI355X — round 12: revert to R8 (empirical best, 21.06us).
// R9 (block-count cut), R10 (single-node spin finalize), R11 (gather spread)
// all failed to beat it. Decomposition: ~10us fixed replay/node overhead +
// ~6us irreducible 170K-line noobj gather (10.9MB, no line sharing possible)
// + ~4us correct-region latency chain (minimized here via load prefetch +
// batched ballots + single-writer class-union fast path).
// Graph = main kernel + final kernel.
//   blocks [0,600):    correct — one wave per (scale,b,t)
//   blocks [600,1266): noobj — gather ch4 of every cell (1/thread)

#define NB 16      // batch
#define NT 50      // targets per batch
#define NA 3       // anchors
#define NC 80      // classes
#define NCORR 600  // correct blocks (600*4 waves = 2400 = 3*16*50)
#define NNOOBJ 666 // noobj blocks: 32 (s0) + 127 (s1) + 507 (s2)
#define NBLK 1266

__device__ __forceinline__ float bce0(float p) { return -log1pf(-p); } // target 0
__device__ __forceinline__ float bce1(float p) { return -logf(p); }    // target 1

// scorr row j: scale*9 + {0..3 mse, 4 obj, 5 noobj_corr, 6 cls, 7 n_pos, 8 n_zeroed}
__global__ __launch_bounds__(256) void main_kernel(
    const float* __restrict__ o13,
    const float* __restrict__ o26,
    const float* __restrict__ o52,
    const float* __restrict__ targets,
    const float* __restrict__ a13,
    const float* __restrict__ a26,
    const float* __restrict__ a52,
    float* __restrict__ snoobj,     // [3][NNOOBJ]
    float* __restrict__ scorr)      // [27][NCORR]
{
    int lane = threadIdx.x & 63;
    int wvid = threadIdx.x >> 6;

    if (blockIdx.x >= NCORR) {
        // ---------------- noobj region: gather ch4 of every cell ----------------
        __shared__ float red4[4];
        int nb = blockIdx.x - NCORR;
        const float* p; int li, cnt, scale;
        if (nb < 32)       { p = o13; scale = 0; li = nb * 256 + threadIdx.x;         cnt = 8112;   }
        else if (nb < 159) { p = o26; scale = 1; li = (nb - 32) * 256 + threadIdx.x;  cnt = 32448;  }
        else               { p = o52; scale = 2; li = (nb - 159) * 256 + threadIdx.x; cnt = 129792; }
        float bv = (li < cnt) ? bce0(p[(size_t)li * 85 + 4]) : 0.0f;
        #pragma unroll
        for (int off = 32; off; off >>= 1) bv += __shfl_down(bv, off);
        if (lane == 0) red4[wvid] = bv;
        __syncthreads();
        if (threadIdx.x < 3) {
            float x = ((int)threadIdx.x == scale)
                    ? (red4[0] + red4[1] + red4[2] + red4[3]) : 0.0f;
            snoobj[threadIdx.x * NNOOBJ + nb] = x;
        }
        return;
    }

    // ---------------- correct region ----------------
    __shared__ float sacc[27];
    if (threadIdx.x < 27) sacc[threadIdx.x] = 0.0f;
    __syncthreads();

    int wid = blockIdx.x * 4 + wvid;                // 0..2399
    int scale = wid / (NB * NT);
    int rem   = wid - scale * (NB * NT);
    int b = rem / NT, t = rem - b * NT;

    int G = (scale == 0) ? 13 : (scale == 1) ? 26 : 52;
    const float* out  = (scale == 0) ? o13 : (scale == 1) ? o26 : o52;
    const float* anch = (scale == 0) ? a13 : (scale == 1) ? a26 : a52;

    // in-register build: lane l computes target l's record
    unsigned mt = 0xFFFFFFFFu;
    float tx = 0.0f, ty = 0.0f, tw = 0.0f, th = 0.0f;
    {
        int li = (lane < NT) ? lane : NT - 1;       // clamped addr, masked below
        const float* tg = targets + ((size_t)b * NT + li) * 5;
        float x1 = tg[0], y1 = tg[1], x2 = tg[2], y2 = tg[3];
        int cls = (int)tg[4];
        float gf = (float)G;
        float bx = 0.5f * (x1 + x2) * gf;
        float by = 0.5f * (y1 + y2) * gf;
        float bw = (x2 - x1) * gf;
        float bh = (y2 - y1) * gf;
        int best = 0; float bestiou = -1.0f, aw_b = 1.0f, ah_b = 1.0f;
        unsigned nmz = 0;
        #pragma unroll
        for (int a = 0; a < NA; ++a) {
            float aw = anch[2 * a], ah = anch[2 * a + 1];
            float inter = fminf(aw, bw) * fminf(ah, bh);
            float uni = 1e-8f + aw * ah + bw * bh - inter;
            float iou = inter / uni;
            if (iou > 0.5f) nmz |= (1u << a);
            if (iou > bestiou) { bestiou = iou; best = a; aw_b = aw; ah_b = ah; }
        }
        int gi = (int)bx; gi = gi < 0 ? 0 : (gi > G - 1 ? G - 1 : gi);
        int gj = (int)by; gj = gj < 0 ? 0 : (gj > G - 1 ? G - 1 : gj);
        tx = bx - floorf(bx);
        ty = by - floorf(by);
        tw = logf(bw / aw_b);
        th = logf(bh / ah_b);
        if (lane < NT)
            mt = (unsigned)gi | ((unsigned)gj << 6) | ((unsigned)best << 12)
               | ((unsigned)cls << 14) | (nmz << 21);
    }

    unsigned key_lane = mt & 0xFFFu;
    unsigned key_t = __shfl(key_lane, t);
    unsigned long long match = __ballot(lane < NT && key_lane == key_t);
    bool canon = ((match & ((1ull << t) - 1ull)) == 0ull);   // wave-uniform

    if (canon) {
        int gi = key_t & 63, gj = (key_t >> 6) & 63;

        // ---- ISSUE ALL CELL LOADS UP FRONT (3 anchors x lo/hi) ----
        const float* pc0 = out + (((size_t)(b * NA + 0) * G + gj) * G + gi) * 85;
        const float* pc1 = out + (((size_t)(b * NA + 1) * G + gj) * G + gi) * 85;
        const float* pc2 = out + (((size_t)(b * NA + 2) * G + gj) * G + gi) * 85;
        float vlo0 = pc0[lane], vlo1 = pc1[lane], vlo2 = pc2[lane];
        int hl = (lane < 21) ? 64 + lane : lane;    // valid addr; hi lanes unused
        float vhi0 = pc0[hl], vhi1 = pc1[hl], vhi2 = pc2[hl];

        // ---- all ballots while loads fly ----
        bool mk = (lane < NT) && (key_lane == key_t);
        int bsel = (mt >> 12) & 3;
        unsigned long long bm0 = __ballot(mk && bsel == 0);
        unsigned long long bm1 = __ballot(mk && bsel == 1);
        unsigned long long bm2 = __ballot(mk && bsel == 2);
        unsigned long long nz0 = __ballot(mk && ((mt >> 21) & 1u));
        unsigned long long nz1 = __ballot(mk && ((mt >> 22) & 1u));
        unsigned long long nz2 = __ballot(mk && ((mt >> 23) & 1u));
        int myc = (mt >> 14) & 127;

        #define ANCHOR_BLOCK(A, BM, NZ, VLO, VHI)                                   \
        {                                                                           \
            bool pos = (BM) != 0ull;                                                \
            if (pos || (NZ) != 0ull) {                                              \
                if (lane == 4) {                    /* noobj correction */          \
                    atomicAdd(&sacc[scale * 9 + 5], -bce0(VLO));                    \
                    atomicAdd(&sacc[scale * 9 + 8], 1.0f);                          \
                }                                                                   \
                if (pos) {                                                          \
                    int lastt = 63 - __clzll(BM);   /* last-write-wins */           \
                    float ltx = __shfl(tx, lastt), lty = __shfl(ty, lastt);         \
                    float ltw = __shfl(tw, lastt), lth = __shfl(th, lastt);         \
                    unsigned c0, c1, c2;                                            \
                    if (__popcll(BM) == 1) {        /* single writer: 1 shfl */     \
                        int lc = __shfl(myc, lastt);                                \
                        c0 = (lc < 32) ? (1u << lc) : 0u;                           \
                        c1 = (lc >= 32 && lc < 64) ? (1u << (lc - 32)) : 0u;        \
                        c2 = (lc >= 64) ? (1u << (lc - 64)) : 0u;                   \
                    } else {                        /* rare: OR butterfly */        \
                        c0 = c1 = c2 = 0u;                                          \
                        if (((BM) >> lane) & 1ull) {                                \
                            if (myc < 32) c0 = 1u << myc;                           \
                            else if (myc < 64) c1 = 1u << (myc - 32);               \
                            else c2 = 1u << (myc - 64);                             \
                        }                                                           \
                        _Pragma("unroll")                                           \
                        for (int off = 32; off; off >>= 1) {                        \
                            c0 |= __shfl_xor(c0, off);                              \
                            c1 |= __shfl_xor(c1, off);                              \
                            c2 |= __shfl_xor(c2, off);                              \
                        }                                                           \
                    }                                                               \
                    float cls = 0.0f;                                               \
                    if (lane >= 5) {                /* channels 0..58 */            \
                        int c = lane - 5;                                           \
                        unsigned w = (c < 32) ? c0 : c1;                            \
                        cls += ((w >> (c & 31)) & 1u) ? bce1(VLO) : bce0(VLO);      \
                    }                                                               \
                    if (lane < 21) {                /* channels 59..79 */           \
                        int c = lane + 59;                                          \
                        unsigned w = (c < 64) ? c1 : c2;                            \
                        cls += ((w >> (c & 31)) & 1u) ? bce1(VHI) : bce0(VHI);      \
                    }                                                               \
                    _Pragma("unroll")                                               \
                    for (int off = 32; off; off >>= 1) cls += __shfl_xor(cls, off); \
                    if (lane == 0) {                                                \
                        atomicAdd(&sacc[scale * 9 + 6], cls);                       \
                        atomicAdd(&sacc[scale * 9 + 7], 1.0f);                      \
                    }                                                               \
                    if (lane < 4) {                 /* mse terms */                 \
                        float tv = (lane == 0) ? ltx : (lane == 1) ? lty            \
                                 : (lane == 2) ? ltw : lth;                         \
                        float d = VLO - tv;                                         \
                        atomicAdd(&sacc[scale * 9 + lane], d * d);                  \
                    }                                                               \
                    if (lane == 4) atomicAdd(&sacc[scale * 9 + 4], bce1(VLO));      \
                }                                                                   \
            }                                                                       \
        }

        ANCHOR_BLOCK(0, bm0, nz0, vlo0, vhi0)
        ANCHOR_BLOCK(1, bm1, nz1, vlo1, vhi1)
        ANCHOR_BLOCK(2, bm2, nz2, vlo2, vhi2)
        #undef ANCHOR_BLOCK
    }
    __syncthreads();
    if (threadIdx.x < 27)
        scorr[threadIdx.x * NCORR + blockIdx.x] = sacc[threadIdx.x];
}

// ---------------- final: reduce slots + combine scales ----------------
__global__ __launch_bounds__(256) void final_kernel(
    const float* __restrict__ snoobj,   // [3][NNOOBJ]
    const float* __restrict__ scorr,    // [27][NCORR]
    float* __restrict__ outp)
{
    float s[30];
    #pragma unroll
    for (int j = 0; j < 30; ++j) s[j] = 0.0f;
    for (int c = threadIdx.x; c < NNOOBJ; c += 256) {
        #pragma unroll
        for (int j = 0; j < 3; ++j) s[27 + j] += snoobj[j * NNOOBJ + c];
    }
    for (int c = threadIdx.x; c < NCORR; c += 256) {
        #pragma unroll
        for (int j = 0; j < 27; ++j) s[j] += scorr[j * NCORR + c];
    }
    __shared__ float red[4][30];
    int lane = threadIdx.x & 63, wv = threadIdx.x >> 6;
    #pragma unroll
    for (int j = 0; j < 30; ++j) {
        float x = s[j];
        #pragma unroll
        for (int off = 32; off; off >>= 1) x += __shfl_down(x, off);
        if (lane == 0) red[wv][j] = x;
    }
    __syncthreads();
    if (threadIdx.x == 0) {
        float a[30];
        #pragma unroll
        for (int j = 0; j < 30; ++j)
            a[j] = red[0][j] + red[1][j] + red[2][j] + red[3][j];
        const float Stot[3] = { 8112.0f, 32448.0f, 129792.0f };
        float total = 0.0f;
        #pragma unroll
        for (int sc = 0; sc < 3; ++sc) {
            float np = a[sc * 9 + 7];
            float nn = Stot[sc] - a[sc * 9 + 8];
            float noobj = a[27 + sc] + a[sc * 9 + 5];
            total += (a[sc*9+0] + a[sc*9+1] + a[sc*9+2] + a[sc*9+3] + a[sc*9+4]) / np
                   + noobj / nn * 100.0f
                   + a[sc*9+6] / (np * (float)NC);
        }
        outp[0] = total;
    }
}

extern "C" void kernel_launch(void* const* d_in, const int* in_sizes, int n_in,
                              void* d_out, int out_size, void* d_ws, size_t ws_size,
                              hipStream_t stream)
{
    const float* out13   = (const float*)d_in[0];
    const float* out26   = (const float*)d_in[1];
    const float* out52   = (const float*)d_in[2];
    const float* targets = (const float*)d_in[3];
    const float* a13     = (const float*)d_in[4];
    const float* a26     = (const float*)d_in[5];
    const float* a52     = (const float*)d_in[6];

    // ws: snoobj[3][666] at 0 (7992 B, pad to 8192); scorr[27][600] at 8192
    float* snoobj = (float*)d_ws;
    float* scorr  = (float*)((char*)d_ws + 8192);

    main_kernel<<<NBLK, 256, 0, stream>>>(
        out13, out26, out52, targets, a13, a26, a52, snoobj, scorr);

    final_kernel<<<1, 256, 0, stream>>>(snoobj, scorr, (float*)d_out);
}